// Round 7
// baseline (13283.125 us; speedup 1.0000x reference)
//
#include <hip/hip_runtime.h>
#include <hip/hip_bf16.h>

// SparseConvNet on MI355X — Round 7 (corrected): runtime input-dtype probe.
// R6: pure-bf16 tier ran (ws >= 256 MiB confirmed) and still NaN'd. Clean
// bf16 math has no NaN mechanism; reading fp32 buffers as bf16 does (odd
// elements = random mantissa halves -> guaranteed Inf/NaN). Reference
// setup_inputs is jnp.float32 -> fp32 is the leading hypothesis. A device
// probe decides: x[0..4095] as bf16 bits all in [0,1) => bf16 dataset; any
// violation => fp32. Flag (stats[380], in d_out's head) steers every input
// load and the output store dtype. Internal activations: bf16 ping-pong,
// bufA|bufB = exactly 256 MiB of ws. L6 scale/shift + flag mirrored into
// dead bufA for finalOut (which overwrites d_out incl. the stats block).

#define HW (1024 * 1024)
typedef __hip_bfloat16 bf16;

__device__ __forceinline__ float b2f(bf16 v) { return __bfloat162float(v); }
__device__ __forceinline__ bf16  f2b(float v) { return __float2bfloat16(v); }

__device__ __forceinline__ float ldv(const void* p, int i, bool isf) {
    return isf ? ((const float*)p)[i] : b2f(((const bf16*)p)[i]);
}

__device__ __forceinline__ float wave_reduce(float v) {
    #pragma unroll
    for (int off = 32; off > 0; off >>= 1)
        v += __shfl_down(v, off, 64);
    return v;
}

// ---------------- dtype probe: 1.0 = fp32 dataset, 0.0 = bf16 ----------------
__global__ void probeKernel(const unsigned short* __restrict__ xb,
                            float* __restrict__ stats)
{
    __shared__ int sbad;
    const int tid = threadIdx.x;
    if (tid == 0) sbad = 0;
    __syncthreads();
    int bad = 0;
    for (int i = tid; i < 4096; i += 256) {
        unsigned u = ((unsigned)xb[i]) << 16;
        float v = __uint_as_float(u);
        if (!(v >= 0.f && v < 1.f)) bad = 1;   // catches NaN/Inf/neg/>=1
    }
    if (bad) sbad = 1;
    __syncthreads();
    if (tid == 0) stats[380] = sbad ? 1.f : 0.f;
}

// ---------------- stats epilogue ---------------------------------------------
__device__ __forceinline__ void statsEpilogue(
    float csum[16], float csq[16], float* red, int tid, float* statsCur)
{
    const int wid = tid >> 6, lane = tid & 63;
    #pragma unroll
    for (int co = 0; co < 16; ++co) {
        csum[co] = wave_reduce(csum[co]);
        csq[co]  = wave_reduce(csq[co]);
    }
    if (lane == 0) {
        #pragma unroll
        for (int co = 0; co < 16; ++co) {
            red[wid * 32 + co]      = csum[co];
            red[wid * 32 + 16 + co] = csq[co];
        }
    }
    __syncthreads();
    if (tid < 32) {
        float t = red[tid] + red[32 + tid] + red[64 + tid] + red[96 + tid];
        atomicAdd(&statsCur[tid], t);
    }
}

// ---------------- composed mask tile (separable max over WP window) ----------
template <int TM, int TK, int WP>
__device__ __forceinline__ void buildMaskTile(
    const void* __restrict__ mask0, bool isf, float* sm0, float* vm,
    float* mprev, int bx, int by, int tid)
{
    constexpr int H1 = (TM - 32) / 2;
    constexpr int H2 = (TK - 32) / 2;
    for (int i = tid; i < TM * TM; i += 256) {
        int yy = by - H1 + i / TM, xx = bx - H1 + i % TM;
        float m = 0.f;
        if ((unsigned)yy < 1024u && (unsigned)xx < 1024u)
            m = ldv(mask0, (yy << 10) + xx, isf);
        sm0[i] = m;
    }
    __syncthreads();
    for (int i = tid; i < TK * TM; i += 256) {
        int y = i / TM, xc = i % TM;
        float mx = 0.f;
        for (int d = 0; d < WP; ++d) mx = fmaxf(mx, sm0[(y + d) * TM + xc]);
        vm[i] = mx;
    }
    __syncthreads();
    for (int i = tid; i < TK * TK; i += 256) {
        int y = i / TK, xc = i % TK;
        int gy = by - H2 + y, gx = bx - H2 + xc;
        float mx = 0.f;
        if ((unsigned)gy < 1024u && (unsigned)gx < 1024u)
            for (int d = 0; d < WP; ++d) mx = fmaxf(mx, vm[y * TM + xc + d]);
        mprev[i] = mx;
    }
    __syncthreads();
}

__device__ __forceinline__ const void* maskChanPtr(const void* x, int n, bool isf) {
    return isf ? (const void*)((const float*)x + n * 2 * HW + HW)
               : (const void*)((const bf16*)x + n * 2 * HW + HW);
}

// ---------------- layer 1: cin=1, K=11; writes y' = 121*(conv/s) + b ---------
__global__ __launch_bounds__(256) void convFirst(
    const void* __restrict__ x, const void* __restrict__ w1,
    const void* __restrict__ bias, bf16* __restrict__ out,
    float* statsCur, const float* flagp)
{
    constexpr int K = 11, P = 5, TK = 42;
    __shared__ float sdat[TK * TK];
    __shared__ float smask[TK * TK];
    __shared__ float red[128];
    __shared__ float sbv[16];
    const bool isf = (*flagp > 0.5f);
    const int n = blockIdx.z;
    const int bx = blockIdx.x * 32, by = blockIdx.y * 32;
    const int tid = threadIdx.x;
    const int tx = tid & 31, ty0 = (tid >> 5) << 2;

    if (tid < 16) sbv[tid] = ldv(bias, tid, isf);

    const int xoff = n * 2 * HW;
    for (int i = tid; i < TK * TK; i += 256) {
        int yy = by - P + i / TK, xx = bx - P + i % TK;
        float d = 0.f, m = 0.f;
        if ((unsigned)yy < 1024u && (unsigned)xx < 1024u) {
            d = ldv(x, xoff + (yy << 10) + xx, isf);
            m = ldv(x, xoff + HW + (yy << 10) + xx, isf);
        }
        sdat[i] = d * m;
        smask[i] = m;
    }
    __syncthreads();

    float inv[4];
    #pragma unroll
    for (int p = 0; p < 4; ++p) {
        float s = 0.f;
        for (int dy = 0; dy < K; ++dy)
            #pragma unroll
            for (int dx = 0; dx < K; ++dx)
                s += smask[(ty0 + p + dy) * TK + tx + dx];
        inv[p] = 121.f / (s + 1e-8f);
    }

    float acc[4][16];
    #pragma unroll
    for (int p = 0; p < 4; ++p)
        #pragma unroll
        for (int co = 0; co < 16; ++co) acc[p][co] = 0.f;

    for (int dy = 0; dy < K; ++dy) {
        for (int dx = 0; dx < K; ++dx) {
            float wv[16];
            #pragma unroll
            for (int co = 0; co < 16; ++co)
                wv[co] = ldv(w1, co * 121 + dy * K + dx, isf);
            const float* sp = sdat + (ty0 + dy) * TK + tx + dx;
            #pragma unroll
            for (int p = 0; p < 4; ++p) {
                float v = sp[p * TK];
                #pragma unroll
                for (int co = 0; co < 16; ++co)
                    acc[p][co] = fmaf(v, wv[co], acc[p][co]);
            }
        }
    }

    float csum[16], csq[16];
    #pragma unroll
    for (int co = 0; co < 16; ++co) { csum[co] = 0.f; csq[co] = 0.f; }
    #pragma unroll
    for (int p = 0; p < 4; ++p) {
        int yy = by + ty0 + p, xx = bx + tx;
        #pragma unroll
        for (int co = 0; co < 16; ++co) {
            float y = fmaf(acc[p][co], inv[p], sbv[co]);
            out[(n * 16 + co) * HW + (yy << 10) + xx] = f2b(y);
            csum[co] += y;
            csq[co] = fmaf(y, y, csq[co]);
        }
    }
    statsEpilogue(csum, csq, red, tid, statsCur);
}

// ---------------- layers 2..5: cin=16, cout=16 -------------------------------
template <int K, int WP>
__global__ __launch_bounds__(256) void conv16(
    const bf16* __restrict__ in, const void* __restrict__ x,
    const void* __restrict__ wL, const float* statsPrev,
    const void* __restrict__ bias, bf16* __restrict__ out,
    float* statsCur, const float* flagp)
{
    constexpr int TK = 32 + K - 1;
    constexpr int TM = TK + WP - 1;
    __shared__ float sm0[TM * TM];
    __shared__ float vm[TK * TM];
    __shared__ float mprev[TK * TK];
    __shared__ float sin_[4 * TK * TK];
    __shared__ float red[128];
    __shared__ float ssc[16], ssh[16], sbv[16];
    constexpr int H2 = (TK - 32) / 2;
    const bool isf = (*flagp > 0.5f);
    const int n = blockIdx.z;
    const int bx = blockIdx.x * 32, by = blockIdx.y * 32;
    const int tid = threadIdx.x;
    const int tx = tid & 31, ty0 = (tid >> 5) << 2;

    if (tid < 16) {
        ssc[tid] = statsPrev[32 + tid];
        ssh[tid] = statsPrev[48 + tid];
        sbv[tid] = ldv(bias, tid, isf);
    }

    buildMaskTile<TM, TK, WP>(maskChanPtr(x, n, isf), isf, sm0, vm, mprev, bx, by, tid);

    float inv[4];
    #pragma unroll
    for (int p = 0; p < 4; ++p) {
        float s = 0.f;
        for (int dy = 0; dy < K; ++dy)
            #pragma unroll
            for (int dx = 0; dx < K; ++dx)
                s += mprev[(ty0 + p + dy) * TK + tx + dx];
        inv[p] = (float)(K * K) / (s + 1e-8f);
    }

    float acc[4][16];
    #pragma unroll
    for (int p = 0; p < 4; ++p)
        #pragma unroll
        for (int co = 0; co < 16; ++co) acc[p][co] = 0.f;

    for (int cc = 0; cc < 4; ++cc) {
        __syncthreads();
        for (int i = tid; i < 4 * TK * TK; i += 256) {
            int c = i / (TK * TK), r = i - c * (TK * TK);
            int yy = by - H2 + r / TK, xx = bx - H2 + r % TK;
            float v = 0.f;
            if ((unsigned)yy < 1024u && (unsigned)xx < 1024u) {
                int ch = cc * 4 + c;
                float y = b2f(in[(n * 16 + ch) * HW + (yy << 10) + xx]);
                float h = fmaxf(fmaf(ssc[ch], y, ssh[ch]), 0.f);
                v = h * mprev[r];
            }
            sin_[i] = v;
        }
        __syncthreads();

        #pragma unroll
        for (int c = 0; c < 4; ++c) {
            const int ch = cc * 4 + c;
            for (int dy = 0; dy < K; ++dy) {
                for (int dx = 0; dx < K; ++dx) {
                    float wv[16];
                    #pragma unroll
                    for (int co = 0; co < 16; ++co)
                        wv[co] = ldv(wL, ((co * 16 + ch) * K + dy) * K + dx, isf);
                    const float* sp = sin_ + c * TK * TK + (ty0 + dy) * TK + tx + dx;
                    #pragma unroll
                    for (int p = 0; p < 4; ++p) {
                        float v = sp[p * TK];
                        #pragma unroll
                        for (int co = 0; co < 16; ++co)
                            acc[p][co] = fmaf(v, wv[co], acc[p][co]);
                    }
                }
            }
        }
    }

    float csum[16], csq[16];
    #pragma unroll
    for (int co = 0; co < 16; ++co) { csum[co] = 0.f; csq[co] = 0.f; }
    #pragma unroll
    for (int p = 0; p < 4; ++p) {
        int yy = by + ty0 + p, xx = bx + tx;
        #pragma unroll
        for (int co = 0; co < 16; ++co) {
            float y = fmaf(acc[p][co], inv[p], sbv[co]);
            out[(n * 16 + co) * HW + (yy << 10) + xx] = f2b(y);
            csum[co] += y;
            csq[co] = fmaf(y, y, csq[co]);
        }
    }
    statsEpilogue(csum, csq, red, tid, statsCur);
}

// ---------------- layer 6: 1x1 conv to 1 channel -----------------------------
__global__ __launch_bounds__(256) void layer6Kernel(
    const bf16* __restrict__ in, const void* __restrict__ x,
    const float* statsPrev, const void* __restrict__ w6,
    const void* __restrict__ b6, bf16* __restrict__ y6,
    float* statsCur, const float* flagp)
{
    constexpr int WP = 25, TM = 56, TK = 32;
    __shared__ float sm0[TM * TM];
    __shared__ float vm[TK * TM];
    __shared__ float m5[TK * TK];
    __shared__ float red[8];
    __shared__ float ssc[16], ssh[16];
    const bool isf = (*flagp > 0.5f);
    const int n = blockIdx.z;
    const int bx = blockIdx.x * 32, by = blockIdx.y * 32;
    const int tid = threadIdx.x;
    const int tx = tid & 31, ty0 = (tid >> 5) << 2;

    if (tid < 16) {
        ssc[tid] = statsPrev[32 + tid];
        ssh[tid] = statsPrev[48 + tid];
    }

    buildMaskTile<TM, TK, WP>(maskChanPtr(x, n, isf), isf, sm0, vm, m5, bx, by, tid);

    float wv[16];
    #pragma unroll
    for (int c = 0; c < 16; ++c) wv[c] = ldv(w6, c, isf);
    const float bias = ldv(b6, 0, isf);

    float lsum = 0.f, lsq = 0.f;
    #pragma unroll
    for (int p = 0; p < 4; ++p) {
        int yy = by + ty0 + p, xx = bx + tx;
        float m = m5[(ty0 + p) * TK + tx];
        float a = 0.f;
        #pragma unroll
        for (int c = 0; c < 16; ++c) {
            float y = b2f(in[(n * 16 + c) * HW + (yy << 10) + xx]);
            float h = fmaxf(fmaf(ssc[c], y, ssh[c]), 0.f);
            a = fmaf(h, wv[c], a);
        }
        float yv = a * m / (m + 1e-8f) + bias;
        y6[n * HW + (yy << 10) + xx] = f2b(yv);
        lsum += yv;
        lsq = fmaf(yv, yv, lsq);
    }
    lsum = wave_reduce(lsum);
    lsq = wave_reduce(lsq);
    const int wid = tid >> 6, lane = tid & 63;
    if (lane == 0) { red[wid] = lsum; red[4 + wid] = lsq; }
    __syncthreads();
    if (tid == 0) atomicAdd(&statsCur[0],  red[0] + red[1] + red[2] + red[3]);
    if (tid == 1) atomicAdd(&statsCur[16], red[4] + red[5] + red[6] + red[7]);
}

// ---------------- helpers ----------------------------------------------------
__global__ void finalizeStats(float* stats, const void* __restrict__ g,
                              const void* __restrict__ bt, float alpha, int cout,
                              float* mirror, const float* flagp)
{
    const bool isf = (*flagp > 0.5f);
    int c = threadIdx.x;
    if (c < cout) {
        const float invN = 1.f / (4.f * HW);
        float meanp = stats[c] * invN;
        float varp  = fmaxf(stats[16 + c] * invN - meanp * meanp, 0.f);
        float var_t = varp / (alpha * alpha);
        float sct = ldv(g, c, isf) * rsqrtf(var_t + 1e-5f);
        float scp = sct / alpha;
        float shp = ldv(bt, c, isf) - scp * meanp;
        stats[32 + c] = scp;
        stats[48 + c] = shp;
        if (mirror) { mirror[2 * c] = scp; mirror[2 * c + 1] = shp; mirror[32] = isf ? 1.f : 0.f; }
    }
}

__global__ void finalOut(const bf16* __restrict__ y6, const float* mirror,
                         void* __restrict__ out)
{
    float sc = mirror[0], sh = mirror[1];
    const bool isf = (mirror[32] > 0.5f);
    for (int idx = blockIdx.x * 256 + threadIdx.x; idx < 4 * HW; idx += gridDim.x * 256) {
        float v = fmaf(b2f(y6[idx]), sc, sh);
        if (isf) ((float*)out)[idx] = v;
        else     ((bf16*)out)[idx] = f2b(v);
    }
}

__global__ void zeroStats(float* stats)
{
    int i = blockIdx.x * 256 + threadIdx.x;
    if (i < 384) stats[i] = 0.f;
}

__global__ void fillOut(void* out, const float* flagp, float v)
{
    const bool isf = (*flagp > 0.5f);
    for (int idx = blockIdx.x * 256 + threadIdx.x; idx < 4 * HW; idx += gridDim.x * 256) {
        if (isf) ((float*)out)[idx] = v;
        else     ((bf16*)out)[idx] = f2b(v);
    }
}

// ---------------- launch ------------------------------------------------------
extern "C" void kernel_launch(void* const* d_in, const int* in_sizes, int n_in,
                              void* d_out, int out_size, void* d_ws, size_t ws_size,
                              hipStream_t stream)
{
    const void* x = d_in[0];
    #define W(L)  ((const void*)d_in[1 + ((L) - 1) * 4])
    #define B(L)  ((const void*)d_in[2 + ((L) - 1) * 4])
    #define G(L)  ((const void*)d_in[3 + ((L) - 1) * 4])
    #define BT(L) ((const void*)d_in[4 + ((L) - 1) * 4])

    float* stats = (float*)d_out;         // 384 floats at d_out head; flag at [380]
    const float* flagp = stats + 380;
    const size_t need = 2 * (size_t)64 * HW * sizeof(bf16);   // exactly 256 MiB

    zeroStats<<<2, 256, 0, stream>>>(stats);
    probeKernel<<<1, 256, 0, stream>>>((const unsigned short*)x, stats);

    if (ws_size < need) {
        fillOut<<<2048, 256, 0, stream>>>(d_out, flagp, 3.0f);  // diagnostic
        return;
    }

    bf16* bufA = (bf16*)d_ws;             // 128 MiB
    bf16* bufB = bufA + 64 * HW;          // 128 MiB
    float* mirror = (float*)bufA;         // written only after bufA is dead

    dim3 grid(32, 32, 4), block(256);

    convFirst<<<grid, block, 0, stream>>>(x, W(1), B(1), bufA, stats + 0, flagp);
    finalizeStats<<<1, 64, 0, stream>>>(stats + 0, G(1), BT(1), 121.f, 16, nullptr, flagp);

    conv16<7, 11><<<grid, block, 0, stream>>>(bufA, x, W(2), stats + 0, B(2), bufB, stats + 64, flagp);
    finalizeStats<<<1, 64, 0, stream>>>(stats + 64, G(2), BT(2), 49.f, 16, nullptr, flagp);

    conv16<5, 17><<<grid, block, 0, stream>>>(bufB, x, W(3), stats + 64, B(3), bufA, stats + 128, flagp);
    finalizeStats<<<1, 64, 0, stream>>>(stats + 128, G(3), BT(3), 25.f, 16, nullptr, flagp);

    conv16<3, 21><<<grid, block, 0, stream>>>(bufA, x, W(4), stats + 128, B(4), bufB, stats + 192, flagp);
    finalizeStats<<<1, 64, 0, stream>>>(stats + 192, G(4), BT(4), 9.f, 16, nullptr, flagp);

    conv16<3, 23><<<grid, block, 0, stream>>>(bufB, x, W(5), stats + 192, B(5), bufA, stats + 256, flagp);
    finalizeStats<<<1, 64, 0, stream>>>(stats + 256, G(5), BT(5), 9.f, 16, nullptr, flagp);

    bf16* y6 = (bf16*)bufB;               // 8 MiB scratch in dead bufB
    layer6Kernel<<<grid, block, 0, stream>>>(bufA, x, stats + 256, W(6), B(6), y6, stats + 320, flagp);
    finalizeStats<<<1, 64, 0, stream>>>(stats + 320, G(6), BT(6), 1.f, 1, mirror, flagp);
    finalOut<<<2048, 256, 0, stream>>>(y6, mirror, d_out);

    #undef W
    #undef B
    #undef G
    #undef BT
}

// Round 8
// 4435.115 us; speedup vs baseline: 2.9950x; 2.9950x over previous
//
#include <hip/hip_runtime.h>
#include <hip/hip_bf16.h>

// SparseConvNet on MI355X — Round 8: kill the weight-load stall.
// R7 passed (absmax 0.156) but conv16<7> = 6.2ms with VALUBusy 19.6%,
// MfmaUtil 0, HBM 0.85% -> latency-bound on 12,544 per-thread scalar global
// weight loads in the inner loop (dual-dtype ldv blocked s_load/vectorize).
// Fix: transposeW stages fp32 weights [ch*KK+tap][co] in d_out scratch once;
// conv kernels copy the current 4-channel chunk into LDS (coalesced float4)
// and the inner loop reads weights as same-address float4 LDS broadcasts.
// VALU floor for conv16<7> = 667us; predict ~850us (was 6220).
//
// Memory map: d_ws = bufA|bufB (2x128 MiB bf16, exactly 256 MiB).
// d_out head: stats[384] + staged weights (25,488 fl) — dead until finalOut.
// L6 scale/shift+flag mirrored into dead bufA for finalOut.

#define HW (1024 * 1024)
typedef __hip_bfloat16 bf16;

__device__ __forceinline__ float b2f(bf16 v) { return __bfloat162float(v); }
__device__ __forceinline__ bf16  f2b(float v) { return __float2bfloat16(v); }

__device__ __forceinline__ float ldv(const void* p, int i, bool isf) {
    return isf ? ((const float*)p)[i] : b2f(((const bf16*)p)[i]);
}

__device__ __forceinline__ float wave_reduce(float v) {
    #pragma unroll
    for (int off = 32; off > 0; off >>= 1)
        v += __shfl_down(v, off, 64);
    return v;
}

// ---------------- dtype probe: 1.0 = fp32 dataset, 0.0 = bf16 ----------------
__global__ void probeKernel(const unsigned short* __restrict__ xb,
                            float* __restrict__ stats)
{
    __shared__ int sbad;
    const int tid = threadIdx.x;
    if (tid == 0) sbad = 0;
    __syncthreads();
    int bad = 0;
    for (int i = tid; i < 4096; i += 256) {
        unsigned u = ((unsigned)xb[i]) << 16;
        float v = __uint_as_float(u);
        if (!(v >= 0.f && v < 1.f)) bad = 1;
    }
    if (bad) sbad = 1;
    __syncthreads();
    if (tid == 0) stats[380] = sbad ? 1.f : 0.f;
}

// ---------------- weight transpose: wt[(ch*KK+tap)*16+co] = w[co][ch][tap] ---
__global__ void transposeW(const void* __restrict__ w, float* __restrict__ wt,
                           int CINKK, const float* flagp)
{
    const bool isf = (*flagp > 0.5f);
    int j = blockIdx.x * 256 + threadIdx.x;
    if (j < 16 * CINKK) {
        int co = j / CINKK, r = j - co * CINKK;
        wt[r * 16 + co] = ldv(w, j, isf);
    }
}

// ---------------- stats epilogue ---------------------------------------------
__device__ __forceinline__ void statsEpilogue(
    float csum[16], float csq[16], float* red, int tid, float* statsCur)
{
    const int wid = tid >> 6, lane = tid & 63;
    #pragma unroll
    for (int co = 0; co < 16; ++co) {
        csum[co] = wave_reduce(csum[co]);
        csq[co]  = wave_reduce(csq[co]);
    }
    if (lane == 0) {
        #pragma unroll
        for (int co = 0; co < 16; ++co) {
            red[wid * 32 + co]      = csum[co];
            red[wid * 32 + 16 + co] = csq[co];
        }
    }
    __syncthreads();
    if (tid < 32) {
        float t = red[tid] + red[32 + tid] + red[64 + tid] + red[96 + tid];
        atomicAdd(&statsCur[tid], t);
    }
}

// ---------------- composed mask tile (separable max over WP window) ----------
template <int TM, int TK, int WP>
__device__ __forceinline__ void buildMaskTile(
    const void* __restrict__ mask0, bool isf, float* sm0, float* vm,
    float* mprev, int bx, int by, int tid)
{
    constexpr int H1 = (TM - 32) / 2;
    constexpr int H2 = (TK - 32) / 2;
    for (int i = tid; i < TM * TM; i += 256) {
        int yy = by - H1 + i / TM, xx = bx - H1 + i % TM;
        float m = 0.f;
        if ((unsigned)yy < 1024u && (unsigned)xx < 1024u)
            m = ldv(mask0, (yy << 10) + xx, isf);
        sm0[i] = m;
    }
    __syncthreads();
    for (int i = tid; i < TK * TM; i += 256) {
        int y = i / TM, xc = i % TM;
        float mx = 0.f;
        for (int d = 0; d < WP; ++d) mx = fmaxf(mx, sm0[(y + d) * TM + xc]);
        vm[i] = mx;
    }
    __syncthreads();
    for (int i = tid; i < TK * TK; i += 256) {
        int y = i / TK, xc = i % TK;
        int gy = by - H2 + y, gx = bx - H2 + xc;
        float mx = 0.f;
        if ((unsigned)gy < 1024u && (unsigned)gx < 1024u)
            for (int d = 0; d < WP; ++d) mx = fmaxf(mx, vm[y * TM + xc + d]);
        mprev[i] = mx;
    }
    __syncthreads();
}

__device__ __forceinline__ const void* maskChanPtr(const void* x, int n, bool isf) {
    return isf ? (const void*)((const float*)x + n * 2 * HW + HW)
               : (const void*)((const bf16*)x + n * 2 * HW + HW);
}

// ---------------- layer 1: cin=1, K=11; writes y' = 121*(conv/s) + b ---------
__global__ __launch_bounds__(256) void convFirst(
    const void* __restrict__ x, const float* __restrict__ wt,
    const void* __restrict__ bias, bf16* __restrict__ out,
    float* statsCur, const float* flagp)
{
    constexpr int K = 11, P = 5, TK = 42, KK = 121;
    __shared__ float sdat[TK * TK];
    __shared__ float smask[TK * TK];
    __shared__ float swt[KK * 16];
    __shared__ float red[128];
    __shared__ float sbv[16];
    const bool isf = (*flagp > 0.5f);
    const int n = blockIdx.z;
    const int bx = blockIdx.x * 32, by = blockIdx.y * 32;
    const int tid = threadIdx.x;
    const int tx = tid & 31, ty0 = (tid >> 5) << 2;

    if (tid < 16) sbv[tid] = ldv(bias, tid, isf);
    {   // all weights -> LDS (coalesced float4)
        const float4* g4 = (const float4*)wt;
        float4* s4 = (float4*)swt;
        for (int i = tid; i < KK * 4; i += 256) s4[i] = g4[i];
    }

    const int xoff = n * 2 * HW;
    for (int i = tid; i < TK * TK; i += 256) {
        int yy = by - P + i / TK, xx = bx - P + i % TK;
        float d = 0.f, m = 0.f;
        if ((unsigned)yy < 1024u && (unsigned)xx < 1024u) {
            d = ldv(x, xoff + (yy << 10) + xx, isf);
            m = ldv(x, xoff + HW + (yy << 10) + xx, isf);
        }
        sdat[i] = d * m;
        smask[i] = m;
    }
    __syncthreads();

    float inv[4];
    #pragma unroll
    for (int p = 0; p < 4; ++p) {
        float s = 0.f;
        for (int dy = 0; dy < K; ++dy)
            #pragma unroll
            for (int dx = 0; dx < K; ++dx)
                s += smask[(ty0 + p + dy) * TK + tx + dx];
        inv[p] = 121.f / (s + 1e-8f);
    }

    float acc[4][16];
    #pragma unroll
    for (int p = 0; p < 4; ++p)
        #pragma unroll
        for (int co = 0; co < 16; ++co) acc[p][co] = 0.f;

    for (int dy = 0; dy < K; ++dy) {
        #pragma unroll
        for (int dx = 0; dx < K; ++dx) {
            const float* wr = swt + ((dy * K + dx) << 4);
            float4 wA = *(const float4*)(wr);
            float4 wB = *(const float4*)(wr + 4);
            float4 wC = *(const float4*)(wr + 8);
            float4 wD = *(const float4*)(wr + 12);
            const float* sp = sdat + (ty0 + dy) * TK + tx + dx;
            #pragma unroll
            for (int p = 0; p < 4; ++p) {
                float v = sp[p * TK];
                acc[p][0]  = fmaf(v, wA.x, acc[p][0]);
                acc[p][1]  = fmaf(v, wA.y, acc[p][1]);
                acc[p][2]  = fmaf(v, wA.z, acc[p][2]);
                acc[p][3]  = fmaf(v, wA.w, acc[p][3]);
                acc[p][4]  = fmaf(v, wB.x, acc[p][4]);
                acc[p][5]  = fmaf(v, wB.y, acc[p][5]);
                acc[p][6]  = fmaf(v, wB.z, acc[p][6]);
                acc[p][7]  = fmaf(v, wB.w, acc[p][7]);
                acc[p][8]  = fmaf(v, wC.x, acc[p][8]);
                acc[p][9]  = fmaf(v, wC.y, acc[p][9]);
                acc[p][10] = fmaf(v, wC.z, acc[p][10]);
                acc[p][11] = fmaf(v, wC.w, acc[p][11]);
                acc[p][12] = fmaf(v, wD.x, acc[p][12]);
                acc[p][13] = fmaf(v, wD.y, acc[p][13]);
                acc[p][14] = fmaf(v, wD.z, acc[p][14]);
                acc[p][15] = fmaf(v, wD.w, acc[p][15]);
            }
        }
    }

    float csum[16], csq[16];
    #pragma unroll
    for (int co = 0; co < 16; ++co) { csum[co] = 0.f; csq[co] = 0.f; }
    #pragma unroll
    for (int p = 0; p < 4; ++p) {
        int yy = by + ty0 + p, xx = bx + tx;
        #pragma unroll
        for (int co = 0; co < 16; ++co) {
            float y = fmaf(acc[p][co], inv[p], sbv[co]);
            out[(n * 16 + co) * HW + (yy << 10) + xx] = f2b(y);
            csum[co] += y;
            csq[co] = fmaf(y, y, csq[co]);
        }
    }
    statsEpilogue(csum, csq, red, tid, statsCur);
}

// ---------------- layers 2..5: cin=16, cout=16 -------------------------------
// LDS carve: [mprev TK*TK][overlay: (sm0 TM*TM | vm TK*TM) then sin_ 4*TK*TK]
// [swt chunk 4ch*KK*16][red 128][ssc/ssh/sbv 48].  All <64KB.
template <int K, int WP>
__global__ __launch_bounds__(256) void conv16(
    const bf16* __restrict__ in, const void* __restrict__ x,
    const float* __restrict__ wt, const float* statsPrev,
    const void* __restrict__ bias, bf16* __restrict__ out,
    float* statsCur, const float* flagp)
{
    constexpr int TK = 32 + K - 1;
    constexpr int TM = TK + WP - 1;
    constexpr int KK = K * K;
    constexpr int SZ_MASK = TM * TM + TK * TM;
    constexpr int SZ_SIN  = 4 * TK * TK;
    constexpr int SZ_OVER = SZ_MASK > SZ_SIN ? SZ_MASK : SZ_SIN;
    constexpr int SZ_SWT  = KK * 64;            // 4ch * KK * 16co
    __shared__ float smem[TK * TK + SZ_OVER + SZ_SWT + 128 + 48];
    float* mprev = smem;
    float* over  = smem + TK * TK;
    float* sm0   = over;
    float* vm    = over + TM * TM;
    float* sin_  = over;
    float* swt   = over + SZ_OVER;
    float* red   = swt + SZ_SWT;
    float* ssc   = red + 128;
    float* ssh   = ssc + 16;
    float* sbv   = ssh + 16;
    constexpr int H2 = (TK - 32) / 2;
    const bool isf = (*flagp > 0.5f);
    const int n = blockIdx.z;
    const int bx = blockIdx.x * 32, by = blockIdx.y * 32;
    const int tid = threadIdx.x;
    const int tx = tid & 31, ty0 = (tid >> 5) << 2;

    if (tid < 16) {
        ssc[tid] = statsPrev[32 + tid];
        ssh[tid] = statsPrev[48 + tid];
        sbv[tid] = ldv(bias, tid, isf);
    }

    buildMaskTile<TM, TK, WP>(maskChanPtr(x, n, isf), isf, sm0, vm, mprev, bx, by, tid);

    float inv[4];
    #pragma unroll
    for (int p = 0; p < 4; ++p) {
        float s = 0.f;
        for (int dy = 0; dy < K; ++dy)
            #pragma unroll
            for (int dx = 0; dx < K; ++dx)
                s += mprev[(ty0 + p + dy) * TK + tx + dx];
        inv[p] = (float)(K * K) / (s + 1e-8f);
    }

    float acc[4][16];
    #pragma unroll
    for (int p = 0; p < 4; ++p)
        #pragma unroll
        for (int co = 0; co < 16; ++co) acc[p][co] = 0.f;

    for (int cc = 0; cc < 4; ++cc) {
        __syncthreads();   // overlay + swt reuse guard
        // stage 4 input channels (h = relu(sc*y'+sh), masked)
        for (int i = tid; i < 4 * TK * TK; i += 256) {
            int c = i / (TK * TK), r = i - c * (TK * TK);
            int yy = by - H2 + r / TK, xx = bx - H2 + r % TK;
            float v = 0.f;
            if ((unsigned)yy < 1024u && (unsigned)xx < 1024u) {
                int ch = cc * 4 + c;
                float y = b2f(in[(n * 16 + ch) * HW + (yy << 10) + xx]);
                float h = fmaxf(fmaf(ssc[ch], y, ssh[ch]), 0.f);
                v = h * mprev[r];
            }
            sin_[i] = v;
        }
        // stage this chunk's weights (contiguous fp32, coalesced float4)
        {
            const float4* g4 = (const float4*)(wt + cc * SZ_SWT);
            float4* s4 = (float4*)swt;
            for (int i = tid; i < SZ_SWT / 4; i += 256) s4[i] = g4[i];
        }
        __syncthreads();

        #pragma unroll
        for (int c = 0; c < 4; ++c) {
            for (int dy = 0; dy < K; ++dy) {
                #pragma unroll
                for (int dx = 0; dx < K; ++dx) {
                    const float* wr = swt + ((c * KK + dy * K + dx) << 4);
                    float4 wA = *(const float4*)(wr);
                    float4 wB = *(const float4*)(wr + 4);
                    float4 wC = *(const float4*)(wr + 8);
                    float4 wD = *(const float4*)(wr + 12);
                    const float* sp = sin_ + c * TK * TK + (ty0 + dy) * TK + tx + dx;
                    #pragma unroll
                    for (int p = 0; p < 4; ++p) {
                        float v = sp[p * TK];
                        acc[p][0]  = fmaf(v, wA.x, acc[p][0]);
                        acc[p][1]  = fmaf(v, wA.y, acc[p][1]);
                        acc[p][2]  = fmaf(v, wA.z, acc[p][2]);
                        acc[p][3]  = fmaf(v, wA.w, acc[p][3]);
                        acc[p][4]  = fmaf(v, wB.x, acc[p][4]);
                        acc[p][5]  = fmaf(v, wB.y, acc[p][5]);
                        acc[p][6]  = fmaf(v, wB.z, acc[p][6]);
                        acc[p][7]  = fmaf(v, wB.w, acc[p][7]);
                        acc[p][8]  = fmaf(v, wC.x, acc[p][8]);
                        acc[p][9]  = fmaf(v, wC.y, acc[p][9]);
                        acc[p][10] = fmaf(v, wC.z, acc[p][10]);
                        acc[p][11] = fmaf(v, wC.w, acc[p][11]);
                        acc[p][12] = fmaf(v, wD.x, acc[p][12]);
                        acc[p][13] = fmaf(v, wD.y, acc[p][13]);
                        acc[p][14] = fmaf(v, wD.z, acc[p][14]);
                        acc[p][15] = fmaf(v, wD.w, acc[p][15]);
                    }
                }
            }
        }
    }

    float csum[16], csq[16];
    #pragma unroll
    for (int co = 0; co < 16; ++co) { csum[co] = 0.f; csq[co] = 0.f; }
    #pragma unroll
    for (int p = 0; p < 4; ++p) {
        int yy = by + ty0 + p, xx = bx + tx;
        #pragma unroll
        for (int co = 0; co < 16; ++co) {
            float y = fmaf(acc[p][co], inv[p], sbv[co]);
            out[(n * 16 + co) * HW + (yy << 10) + xx] = f2b(y);
            csum[co] += y;
            csq[co] = fmaf(y, y, csq[co]);
        }
    }
    statsEpilogue(csum, csq, red, tid, statsCur);
}

// ---------------- layer 6: 1x1 conv to 1 channel -----------------------------
__global__ __launch_bounds__(256) void layer6Kernel(
    const bf16* __restrict__ in, const void* __restrict__ x,
    const float* statsPrev, const void* __restrict__ w6,
    const void* __restrict__ b6, bf16* __restrict__ y6,
    float* statsCur, const float* flagp)
{
    constexpr int WP = 25, TM = 56, TK = 32;
    __shared__ float sm0[TM * TM];
    __shared__ float vm[TK * TM];
    __shared__ float m5[TK * TK];
    __shared__ float red[8];
    __shared__ float ssc[16], ssh[16];
    const bool isf = (*flagp > 0.5f);
    const int n = blockIdx.z;
    const int bx = blockIdx.x * 32, by = blockIdx.y * 32;
    const int tid = threadIdx.x;
    const int tx = tid & 31, ty0 = (tid >> 5) << 2;

    if (tid < 16) {
        ssc[tid] = statsPrev[32 + tid];
        ssh[tid] = statsPrev[48 + tid];
    }

    buildMaskTile<TM, TK, WP>(maskChanPtr(x, n, isf), isf, sm0, vm, m5, bx, by, tid);

    float wv[16];
    #pragma unroll
    for (int c = 0; c < 16; ++c) wv[c] = ldv(w6, c, isf);
    const float bias = ldv(b6, 0, isf);

    float lsum = 0.f, lsq = 0.f;
    #pragma unroll
    for (int p = 0; p < 4; ++p) {
        int yy = by + ty0 + p, xx = bx + tx;
        float m = m5[(ty0 + p) * TK + tx];
        float a = 0.f;
        #pragma unroll
        for (int c = 0; c < 16; ++c) {
            float y = b2f(in[(n * 16 + c) * HW + (yy << 10) + xx]);
            float h = fmaxf(fmaf(ssc[c], y, ssh[c]), 0.f);
            a = fmaf(h, wv[c], a);
        }
        float yv = a * m / (m + 1e-8f) + bias;
        y6[n * HW + (yy << 10) + xx] = f2b(yv);
        lsum += yv;
        lsq = fmaf(yv, yv, lsq);
    }
    lsum = wave_reduce(lsum);
    lsq = wave_reduce(lsq);
    const int wid = tid >> 6, lane = tid & 63;
    if (lane == 0) { red[wid] = lsum; red[4 + wid] = lsq; }
    __syncthreads();
    if (tid == 0) atomicAdd(&statsCur[0],  red[0] + red[1] + red[2] + red[3]);
    if (tid == 1) atomicAdd(&statsCur[16], red[4] + red[5] + red[6] + red[7]);
}

// ---------------- helpers ----------------------------------------------------
__global__ void finalizeStats(float* stats, const void* __restrict__ g,
                              const void* __restrict__ bt, float alpha, int cout,
                              float* mirror, const float* flagp)
{
    const bool isf = (*flagp > 0.5f);
    int c = threadIdx.x;
    if (c < cout) {
        const float invN = 1.f / (4.f * HW);
        float meanp = stats[c] * invN;
        float varp  = fmaxf(stats[16 + c] * invN - meanp * meanp, 0.f);
        float var_t = varp / (alpha * alpha);
        float sct = ldv(g, c, isf) * rsqrtf(var_t + 1e-5f);
        float scp = sct / alpha;
        float shp = ldv(bt, c, isf) - scp * meanp;
        stats[32 + c] = scp;
        stats[48 + c] = shp;
        if (mirror) { mirror[2 * c] = scp; mirror[2 * c + 1] = shp; mirror[32] = isf ? 1.f : 0.f; }
    }
}

__global__ void finalOut(const bf16* __restrict__ y6, const float* mirror,
                         void* __restrict__ out)
{
    float sc = mirror[0], sh = mirror[1];
    const bool isf = (mirror[32] > 0.5f);
    for (int idx = blockIdx.x * 256 + threadIdx.x; idx < 4 * HW; idx += gridDim.x * 256) {
        float v = fmaf(b2f(y6[idx]), sc, sh);
        if (isf) ((float*)out)[idx] = v;
        else     ((bf16*)out)[idx] = f2b(v);
    }
}

__global__ void zeroStats(float* stats)
{
    int i = blockIdx.x * 256 + threadIdx.x;
    if (i < 384) stats[i] = 0.f;
}

__global__ void fillOut(void* out, const float* flagp, float v)
{
    const bool isf = (*flagp > 0.5f);
    for (int idx = blockIdx.x * 256 + threadIdx.x; idx < 4 * HW; idx += gridDim.x * 256) {
        if (isf) ((float*)out)[idx] = v;
        else     ((bf16*)out)[idx] = f2b(v);
    }
}

// ---------------- launch ------------------------------------------------------
extern "C" void kernel_launch(void* const* d_in, const int* in_sizes, int n_in,
                              void* d_out, int out_size, void* d_ws, size_t ws_size,
                              hipStream_t stream)
{
    const void* x = d_in[0];
    #define W(L)  ((const void*)d_in[1 + ((L) - 1) * 4])
    #define B(L)  ((const void*)d_in[2 + ((L) - 1) * 4])
    #define G(L)  ((const void*)d_in[3 + ((L) - 1) * 4])
    #define BT(L) ((const void*)d_in[4 + ((L) - 1) * 4])

    float* stats = (float*)d_out;          // 384 floats; flag at [380]
    const float* flagp = stats + 380;
    // staged fp32 weights after stats (offsets all multiples of 16 floats)
    float* wt1 = stats + 384;              // 121*16  = 1936
    float* wt2 = wt1 + 1936;               // 784*16  = 12544
    float* wt3 = wt2 + 12544;              // 400*16  = 6400
    float* wt4 = wt3 + 6400;               // 144*16  = 2304
    float* wt5 = wt4 + 2304;               // 144*16  = 2304
    const size_t need = 2 * (size_t)64 * HW * sizeof(bf16);   // exactly 256 MiB

    zeroStats<<<2, 256, 0, stream>>>(stats);
    probeKernel<<<1, 256, 0, stream>>>((const unsigned short*)x, stats);

    if (ws_size < need) {
        fillOut<<<2048, 256, 0, stream>>>(d_out, flagp, 3.0f);  // diagnostic
        return;
    }

    transposeW<<<8, 256, 0, stream>>>(W(1), wt1, 121, flagp);
    transposeW<<<49, 256, 0, stream>>>(W(2), wt2, 784, flagp);
    transposeW<<<25, 256, 0, stream>>>(W(3), wt3, 400, flagp);
    transposeW<<<9, 256, 0, stream>>>(W(4), wt4, 144, flagp);
    transposeW<<<9, 256, 0, stream>>>(W(5), wt5, 144, flagp);

    bf16* bufA = (bf16*)d_ws;              // 128 MiB
    bf16* bufB = bufA + 64 * HW;           // 128 MiB
    float* mirror = (float*)bufA;          // written only after bufA is dead

    dim3 grid(32, 32, 4), block(256);

    convFirst<<<grid, block, 0, stream>>>(x, wt1, B(1), bufA, stats + 0, flagp);
    finalizeStats<<<1, 64, 0, stream>>>(stats + 0, G(1), BT(1), 121.f, 16, nullptr, flagp);

    conv16<7, 11><<<grid, block, 0, stream>>>(bufA, x, wt2, stats + 0, B(2), bufB, stats + 64, flagp);
    finalizeStats<<<1, 64, 0, stream>>>(stats + 64, G(2), BT(2), 49.f, 16, nullptr, flagp);

    conv16<5, 17><<<grid, block, 0, stream>>>(bufB, x, wt3, stats + 64, B(3), bufA, stats + 128, flagp);
    finalizeStats<<<1, 64, 0, stream>>>(stats + 128, G(3), BT(3), 25.f, 16, nullptr, flagp);

    conv16<3, 21><<<grid, block, 0, stream>>>(bufA, x, wt4, stats + 128, B(4), bufB, stats + 192, flagp);
    finalizeStats<<<1, 64, 0, stream>>>(stats + 192, G(4), BT(4), 9.f, 16, nullptr, flagp);

    conv16<3, 23><<<grid, block, 0, stream>>>(bufB, x, wt5, stats + 192, B(5), bufA, stats + 256, flagp);
    finalizeStats<<<1, 64, 0, stream>>>(stats + 256, G(5), BT(5), 9.f, 16, nullptr, flagp);

    bf16* y6 = (bf16*)bufB;                // 8 MiB scratch in dead bufB
    layer6Kernel<<<grid, block, 0, stream>>>(bufA, x, stats + 256, W(6), B(6), y6, stats + 320, flagp);
    finalizeStats<<<1, 64, 0, stream>>>(stats + 320, G(6), BT(6), 1.f, 1, mirror, flagp);
    finalOut<<<2048, 256, 0, stream>>>(y6, mirror, d_out);

    #undef W
    #undef B
    #undef G
    #undef BT
}

// Round 9
// 1338.909 us; speedup vs baseline: 9.9209x; 3.3125x over previous
//
#include <hip/hip_runtime.h>
#include <hip/hip_bf16.h>

// SparseConvNet on MI355X — Round 9: bf16 MFMA implicit-GEMM for layers 2-5.
// R8: conv16<7> = 2194us, VALUBusy 40%, MfmaUtil 0 -> fp32 VALU (157 TF) is
// the structural ceiling; move the K=784/400/144 dot-products to the bf16
// MFMA pipe (2382 TF). Per wave: 16px x 16cout D-tile, K = (ch,tap) pairs.
// LDS input [pixel][8ch] bf16 (two halves -> A-frag = 1 ds_read_b128,
// 16B stride = 2-way = free). B-frags hoisted to VGPRs from pre-transposed
// [tap][cout][cin] bf16 weights. Taps padded to even; pad tap has zero B and
// clamped (0,0) A address (finite). convFirst/L6 unchanged (VALU).

#define HW (1024 * 1024)
typedef __hip_bfloat16 bf16;
typedef __attribute__((ext_vector_type(8))) short s8v;     // 8 bf16 = 4 VGPR
typedef __attribute__((ext_vector_type(4))) float f4v;     // MFMA acc

__device__ __forceinline__ float b2f(bf16 v) { return __bfloat162float(v); }
__device__ __forceinline__ bf16  f2b(float v) { return __float2bfloat16(v); }
__device__ __forceinline__ short fbits(float v) {
    bf16 t = f2b(v); short s; __builtin_memcpy(&s, &t, 2); return s;
}

__device__ __forceinline__ float ldv(const void* p, int i, bool isf) {
    return isf ? ((const float*)p)[i] : b2f(((const bf16*)p)[i]);
}

__device__ __forceinline__ float wave_reduce(float v) {
    #pragma unroll
    for (int off = 32; off > 0; off >>= 1)
        v += __shfl_down(v, off, 64);
    return v;
}

// ---------------- dtype probe: 1.0 = fp32 dataset, 0.0 = bf16 ----------------
__global__ void probeKernel(const unsigned short* __restrict__ xb,
                            float* __restrict__ stats)
{
    __shared__ int sbad;
    const int tid = threadIdx.x;
    if (tid == 0) sbad = 0;
    __syncthreads();
    int bad = 0;
    for (int i = tid; i < 4096; i += 256) {
        unsigned u = ((unsigned)xb[i]) << 16;
        float v = __uint_as_float(u);
        if (!(v >= 0.f && v < 1.f)) bad = 1;
    }
    if (bad) sbad = 1;
    __syncthreads();
    if (tid == 0) stats[380] = sbad ? 1.f : 0.f;
}

// ---- L1 weights: wt[(tap)*16+co] = w[co][tap], fp32 (for VALU convFirst) ----
__global__ void transposeW(const void* __restrict__ w, float* __restrict__ wt,
                           int CINKK, const float* flagp)
{
    const bool isf = (*flagp > 0.5f);
    int j = blockIdx.x * 256 + threadIdx.x;
    if (j < 16 * CINKK) {
        int co = j / CINKK, r = j - co * CINKK;
        wt[r * 16 + co] = ldv(w, j, isf);
    }
}

// ---- L2-5 weights for MFMA B: wtB[((t*16+co)*16)+c] = w[co][c][t], bf16 -----
// t in [KK, NT) zero-padded.
__global__ void transposeWB(const void* __restrict__ w, bf16* __restrict__ wtB,
                            int KK, int NT, const float* flagp)
{
    const bool isf = (*flagp > 0.5f);
    int j = blockIdx.x * 256 + threadIdx.x;
    if (j < NT * 256) {
        int t = j >> 8, co = (j >> 4) & 15, c = j & 15;
        float v = (t < KK) ? ldv(w, (co * 16 + c) * KK + t, isf) : 0.f;
        wtB[j] = f2b(v);
    }
}

// ---------------- composed mask tile (separable max over WP window) ----------
template <int TM, int TK, int WP>
__device__ __forceinline__ void buildMaskTile(
    const void* __restrict__ mask0, bool isf, float* sm0, float* vm,
    float* mprev, int bx, int by, int tid)
{
    constexpr int H1 = (TM - 32) / 2;
    constexpr int H2 = (TK - 32) / 2;
    for (int i = tid; i < TM * TM; i += 256) {
        int yy = by - H1 + i / TM, xx = bx - H1 + i % TM;
        float m = 0.f;
        if ((unsigned)yy < 1024u && (unsigned)xx < 1024u)
            m = ldv(mask0, (yy << 10) + xx, isf);
        sm0[i] = m;
    }
    __syncthreads();
    for (int i = tid; i < TK * TM; i += 256) {
        int y = i / TM, xc = i % TM;
        float mx = 0.f;
        for (int d = 0; d < WP; ++d) mx = fmaxf(mx, sm0[(y + d) * TM + xc]);
        vm[i] = mx;
    }
    __syncthreads();
    for (int i = tid; i < TK * TK; i += 256) {
        int y = i / TK, xc = i % TK;
        int gy = by - H2 + y, gx = bx - H2 + xc;
        float mx = 0.f;
        if ((unsigned)gy < 1024u && (unsigned)gx < 1024u)
            for (int d = 0; d < WP; ++d) mx = fmaxf(mx, vm[y * TM + xc + d]);
        mprev[i] = mx;
    }
    __syncthreads();
}

__device__ __forceinline__ const void* maskChanPtr(const void* x, int n, bool isf) {
    return isf ? (const void*)((const float*)x + n * 2 * HW + HW)
               : (const void*)((const bf16*)x + n * 2 * HW + HW);
}

// ---------------- layer 1: cin=1, K=11 (VALU, unchanged from R8) -------------
__global__ __launch_bounds__(256) void convFirst(
    const void* __restrict__ x, const float* __restrict__ wt,
    const void* __restrict__ bias, bf16* __restrict__ out,
    float* statsCur, const float* flagp)
{
    constexpr int K = 11, P = 5, TK = 42, KK = 121;
    __shared__ float sdat[TK * TK];
    __shared__ float smask[TK * TK];
    __shared__ float swt[KK * 16];
    __shared__ float red[128];
    __shared__ float sbv[16];
    const bool isf = (*flagp > 0.5f);
    const int n = blockIdx.z;
    const int bx = blockIdx.x * 32, by = blockIdx.y * 32;
    const int tid = threadIdx.x;
    const int tx = tid & 31, ty0 = (tid >> 5) << 2;

    if (tid < 16) sbv[tid] = ldv(bias, tid, isf);
    {
        const float4* g4 = (const float4*)wt;
        float4* s4 = (float4*)swt;
        for (int i = tid; i < KK * 4; i += 256) s4[i] = g4[i];
    }

    const int xoff = n * 2 * HW;
    for (int i = tid; i < TK * TK; i += 256) {
        int yy = by - P + i / TK, xx = bx - P + i % TK;
        float d = 0.f, m = 0.f;
        if ((unsigned)yy < 1024u && (unsigned)xx < 1024u) {
            d = ldv(x, xoff + (yy << 10) + xx, isf);
            m = ldv(x, xoff + HW + (yy << 10) + xx, isf);
        }
        sdat[i] = d * m;
        smask[i] = m;
    }
    __syncthreads();

    float inv[4];
    #pragma unroll
    for (int p = 0; p < 4; ++p) {
        float s = 0.f;
        for (int dy = 0; dy < K; ++dy)
            #pragma unroll
            for (int dx = 0; dx < K; ++dx)
                s += smask[(ty0 + p + dy) * TK + tx + dx];
        inv[p] = 121.f / (s + 1e-8f);
    }

    float acc[4][16];
    #pragma unroll
    for (int p = 0; p < 4; ++p)
        #pragma unroll
        for (int co = 0; co < 16; ++co) acc[p][co] = 0.f;

    for (int dy = 0; dy < K; ++dy) {
        #pragma unroll
        for (int dx = 0; dx < K; ++dx) {
            const float* wr = swt + ((dy * K + dx) << 4);
            float4 wA = *(const float4*)(wr);
            float4 wB = *(const float4*)(wr + 4);
            float4 wC = *(const float4*)(wr + 8);
            float4 wD = *(const float4*)(wr + 12);
            const float* sp = sdat + (ty0 + dy) * TK + tx + dx;
            #pragma unroll
            for (int p = 0; p < 4; ++p) {
                float v = sp[p * TK];
                acc[p][0]  = fmaf(v, wA.x, acc[p][0]);
                acc[p][1]  = fmaf(v, wA.y, acc[p][1]);
                acc[p][2]  = fmaf(v, wA.z, acc[p][2]);
                acc[p][3]  = fmaf(v, wA.w, acc[p][3]);
                acc[p][4]  = fmaf(v, wB.x, acc[p][4]);
                acc[p][5]  = fmaf(v, wB.y, acc[p][5]);
                acc[p][6]  = fmaf(v, wB.z, acc[p][6]);
                acc[p][7]  = fmaf(v, wB.w, acc[p][7]);
                acc[p][8]  = fmaf(v, wC.x, acc[p][8]);
                acc[p][9]  = fmaf(v, wC.y, acc[p][9]);
                acc[p][10] = fmaf(v, wC.z, acc[p][10]);
                acc[p][11] = fmaf(v, wC.w, acc[p][11]);
                acc[p][12] = fmaf(v, wD.x, acc[p][12]);
                acc[p][13] = fmaf(v, wD.y, acc[p][13]);
                acc[p][14] = fmaf(v, wD.z, acc[p][14]);
                acc[p][15] = fmaf(v, wD.w, acc[p][15]);
            }
        }
    }

    float csum[16], csq[16];
    #pragma unroll
    for (int co = 0; co < 16; ++co) { csum[co] = 0.f; csq[co] = 0.f; }
    #pragma unroll
    for (int p = 0; p < 4; ++p) {
        int yy = by + ty0 + p, xx = bx + tx;
        #pragma unroll
        for (int co = 0; co < 16; ++co) {
            float y = fmaf(acc[p][co], inv[p], sbv[co]);
            out[(n * 16 + co) * HW + (yy << 10) + xx] = f2b(y);
            csum[co] += y;
            csq[co] = fmaf(y, y, csq[co]);
        }
    }
    // wave->block->atomic stats
    const int wid = tid >> 6, lane = tid & 63;
    #pragma unroll
    for (int co = 0; co < 16; ++co) {
        csum[co] = wave_reduce(csum[co]);
        csq[co]  = wave_reduce(csq[co]);
    }
    if (lane == 0) {
        #pragma unroll
        for (int co = 0; co < 16; ++co) {
            red[wid * 32 + co]      = csum[co];
            red[wid * 32 + 16 + co] = csq[co];
        }
    }
    __syncthreads();
    if (tid < 32) {
        float t = red[tid] + red[32 + tid] + red[64 + tid] + red[96 + tid];
        atomicAdd(&statsCur[tid], t);
    }
}

// ---------------- layers 2..5: MFMA implicit-GEMM ----------------------------
// Wave computes 16 m-tiles of D[16px][16co]. K = c + 16*t (c=cin, t=tap).
// A[m=lane&15][k=quad*8+j]: 8 consecutive channels at one (pixel,tap) ->
// one ds_read_b128 from [pixel][8ch] half. B[k=quad*8+j][n=lane&15] from
// wtB[t][co][c] global, hoisted. D: col(n)=lane&15, row(m)=quad*4+reg.
template <int K, int WP>
__global__ __launch_bounds__(256) void conv16m(
    const bf16* __restrict__ in, const void* __restrict__ x,
    const bf16* __restrict__ wtB, const float* statsPrev,
    const void* __restrict__ bias, bf16* __restrict__ out,
    float* statsCur, const float* flagp)
{
    constexpr int TK = 32 + K - 1;
    constexpr int TM = TK + WP - 1;
    constexpr int KK = K * K, NT = KK + 1, NK = NT / 2;
    constexpr int H2 = K / 2;
    __shared__ short sdatL[TK * TK * 8];     // [pixel][ch 0-7] bf16
    __shared__ short sdatH[TK * TK * 8];     // [pixel][ch 8-15]
    __shared__ float mprev[TK * TK];
    __shared__ float sinv[1024];             // 32x32 per-pixel K^2/(s+eps)
    __shared__ float red[128];
    __shared__ float sss[32];                // ssc[16] | ssh[16]
    const bool isf = (*flagp > 0.5f);
    const int n = blockIdx.z;
    const int bx = blockIdx.x * 32, by = blockIdx.y * 32;
    const int tid = threadIdx.x, lane = tid & 63, wid = tid >> 6;

    if (tid < 16) { sss[tid] = statsPrev[32 + tid]; sss[16 + tid] = statsPrev[48 + tid]; }

    buildMaskTile<TM, TK, WP>(maskChanPtr(x, n, isf), isf,
                              (float*)sdatL, (float*)sdatH, mprev, bx, by, tid);

    // per-pixel inv (32x32)
    {
        const int tx = tid & 31, ty0 = (tid >> 5) << 2;
        #pragma unroll
        for (int p = 0; p < 4; ++p) {
            float s = 0.f;
            for (int dy = 0; dy < K; ++dy)
                #pragma unroll
                for (int dx = 0; dx < K; ++dx)
                    s += mprev[(ty0 + p + dy) * TK + tx + dx];
            sinv[(ty0 + p) * 32 + tx] = (float)KK / (s + 1e-8f);
        }
    }

    // hoist B fragments (global 16B loads, latency overlapped with staging)
    const int nn = lane & 15, quad = lane >> 4, c0 = (quad & 1) * 8, tl = quad >> 1;
    s8v Bf[NK];
    #pragma unroll
    for (int kk = 0; kk < NK; ++kk) {
        int t = 2 * kk + tl;
        Bf[kk] = *(const s8v*)(wtB + ((t * 16 + nn) * 16 + c0));
    }

    // stage input: h = relu(sc*y'+sh) * mask, bf16, [pixel][8ch] halves
    {
        const bf16* inb = in + (size_t)n * 16 * HW;
        for (int p = tid; p < TK * TK; p += 256) {
            int yy = by - H2 + p / TK, xx = bx - H2 + p % TK;
            s8v lo = {0,0,0,0,0,0,0,0}, hi = {0,0,0,0,0,0,0,0};
            if ((unsigned)yy < 1024u && (unsigned)xx < 1024u) {
                float mv = mprev[p];
                const bf16* q = inb + (yy << 10) + xx;
                #pragma unroll
                for (int c = 0; c < 8; ++c) {
                    float yv = b2f(q[c * HW]);
                    lo[c] = fbits(fmaxf(fmaf(sss[c], yv, sss[16 + c]), 0.f) * mv);
                }
                #pragma unroll
                for (int c = 0; c < 8; ++c) {
                    float yv = b2f(q[(c + 8) * HW]);
                    hi[c] = fbits(fmaxf(fmaf(sss[c + 8], yv, sss[24 + c]), 0.f) * mv);
                }
            }
            ((s8v*)sdatL)[p] = lo;
            ((s8v*)sdatH)[p] = hi;
        }
    }
    __syncthreads();

    const float bv = ldv(bias, nn, isf);
    const s8v* Abase = (const s8v*)((quad & 1) ? sdatH : sdatL);
    const size_t obase = ((size_t)n * 16 + nn) * HW;
    float lsum = 0.f, lsq = 0.f;

    for (int mt = 0; mt < 16; ++mt) {
        int idx = wid * 16 + mt;          // 0..63
        int r = idx >> 1, xh = (idx & 1) << 4;
        int acol = xh + nn;               // x offset + m(lane&15)
        f4v acc0 = {0.f, 0.f, 0.f, 0.f}, acc1 = {0.f, 0.f, 0.f, 0.f};
        #pragma unroll
        for (int kk = 0; kk < NK; ++kk) {
            constexpr_tap:;
            const int ta = (2 * kk < KK) ? 2 * kk : 0;
            const int tb = (2 * kk + 1 < KK) ? 2 * kk + 1 : 0;
            const int dya = ta / K, dxa = ta % K;
            const int dyb = tb / K, dxb = tb % K;
            int dy = tl ? dyb : dya;
            int dx = tl ? dxb : dxa;
            s8v a = Abase[(r + dy) * TK + acol + dx];
            if (kk & 1)
                acc1 = __builtin_amdgcn_mfma_f32_16x16x32_bf16(a, Bf[kk], acc1, 0, 0, 0);
            else
                acc0 = __builtin_amdgcn_mfma_f32_16x16x32_bf16(a, Bf[kk], acc0, 0, 0, 0);
        }
        #pragma unroll
        for (int i = 0; i < 4; ++i) {
            float av = acc0[i] + acc1[i];
            int m = quad * 4 + i;
            float y = fmaf(av, sinv[r * 32 + xh + m], bv);
            out[obase + ((by + r) << 10) + bx + xh + m] = f2b(y);
            lsum += y;
            lsq = fmaf(y, y, lsq);
        }
    }

    // stats: each lane owns cout nn; reduce lanes {nn, nn+16, nn+32, nn+48}
    lsum += __shfl_xor(lsum, 16, 64);
    lsum += __shfl_xor(lsum, 32, 64);
    lsq  += __shfl_xor(lsq, 16, 64);
    lsq  += __shfl_xor(lsq, 32, 64);
    if (lane < 16) {
        red[wid * 32 + lane]      = lsum;
        red[wid * 32 + 16 + lane] = lsq;
    }
    __syncthreads();
    if (tid < 32) {
        float t = red[tid] + red[32 + tid] + red[64 + tid] + red[96 + tid];
        atomicAdd(&statsCur[tid], t);
    }
}

// ---------------- layer 6: 1x1 conv to 1 channel -----------------------------
__global__ __launch_bounds__(256) void layer6Kernel(
    const bf16* __restrict__ in, const void* __restrict__ x,
    const float* statsPrev, const void* __restrict__ w6,
    const void* __restrict__ b6, bf16* __restrict__ y6,
    float* statsCur, const float* flagp)
{
    constexpr int WP = 25, TM = 56, TK = 32;
    __shared__ float sm0[TM * TM];
    __shared__ float vm[TK * TM];
    __shared__ float m5[TK * TK];
    __shared__ float red[8];
    __shared__ float ssc[16], ssh[16];
    const bool isf = (*flagp > 0.5f);
    const int n = blockIdx.z;
    const int bx = blockIdx.x * 32, by = blockIdx.y * 32;
    const int tid = threadIdx.x;
    const int tx = tid & 31, ty0 = (tid >> 5) << 2;

    if (tid < 16) {
        ssc[tid] = statsPrev[32 + tid];
        ssh[tid] = statsPrev[48 + tid];
    }

    buildMaskTile<TM, TK, WP>(maskChanPtr(x, n, isf), isf, sm0, vm, m5, bx, by, tid);

    float wv[16];
    #pragma unroll
    for (int c = 0; c < 16; ++c) wv[c] = ldv(w6, c, isf);
    const float bias = ldv(b6, 0, isf);

    float lsum = 0.f, lsq = 0.f;
    #pragma unroll
    for (int p = 0; p < 4; ++p) {
        int yy = by + ty0 + p, xx = bx + tx;
        float m = m5[(ty0 + p) * TK + tx];
        float a = 0.f;
        #pragma unroll
        for (int c = 0; c < 16; ++c) {
            float y = b2f(in[(n * 16 + c) * HW + (yy << 10) + xx]);
            float h = fmaxf(fmaf(ssc[c], y, ssh[c]), 0.f);
            a = fmaf(h, wv[c], a);
        }
        float yv = a * m / (m + 1e-8f) + bias;
        y6[n * HW + (yy << 10) + xx] = f2b(yv);
        lsum += yv;
        lsq = fmaf(yv, yv, lsq);
    }
    lsum = wave_reduce(lsum);
    lsq = wave_reduce(lsq);
    const int wid = tid >> 6, lane = tid & 63;
    if (lane == 0) { red[wid] = lsum; red[4 + wid] = lsq; }
    __syncthreads();
    if (tid == 0) atomicAdd(&statsCur[0],  red[0] + red[1] + red[2] + red[3]);
    if (tid == 1) atomicAdd(&statsCur[16], red[4] + red[5] + red[6] + red[7]);
}

// ---------------- helpers ----------------------------------------------------
__global__ void finalizeStats(float* stats, const void* __restrict__ g,
                              const void* __restrict__ bt, float alpha, int cout,
                              float* mirror, const float* flagp)
{
    const bool isf = (*flagp > 0.5f);
    int c = threadIdx.x;
    if (c < cout) {
        const float invN = 1.f / (4.f * HW);
        float meanp = stats[c] * invN;
        float varp  = fmaxf(stats[16 + c] * invN - meanp * meanp, 0.f);
        float var_t = varp / (alpha * alpha);
        float sct = ldv(g, c, isf) * rsqrtf(var_t + 1e-5f);
        float scp = sct / alpha;
        float shp = ldv(bt, c, isf) - scp * meanp;
        stats[32 + c] = scp;
        stats[48 + c] = shp;
        if (mirror) { mirror[2 * c] = scp; mirror[2 * c + 1] = shp; mirror[32] = isf ? 1.f : 0.f; }
    }
}

__global__ void finalOut(const bf16* __restrict__ y6, const float* mirror,
                         void* __restrict__ out)
{
    float sc = mirror[0], sh = mirror[1];
    const bool isf = (mirror[32] > 0.5f);
    for (int idx = blockIdx.x * 256 + threadIdx.x; idx < 4 * HW; idx += gridDim.x * 256) {
        float v = fmaf(b2f(y6[idx]), sc, sh);
        if (isf) ((float*)out)[idx] = v;
        else     ((bf16*)out)[idx] = f2b(v);
    }
}

__global__ void zeroStats(float* stats)
{
    int i = blockIdx.x * 256 + threadIdx.x;
    if (i < 384) stats[i] = 0.f;
}

__global__ void fillOut(void* out, const float* flagp, float v)
{
    const bool isf = (*flagp > 0.5f);
    for (int idx = blockIdx.x * 256 + threadIdx.x; idx < 4 * HW; idx += gridDim.x * 256) {
        if (isf) ((float*)out)[idx] = v;
        else     ((bf16*)out)[idx] = f2b(v);
    }
}

// ---------------- launch ------------------------------------------------------
extern "C" void kernel_launch(void* const* d_in, const int* in_sizes, int n_in,
                              void* d_out, int out_size, void* d_ws, size_t ws_size,
                              hipStream_t stream)
{
    const void* x = d_in[0];
    #define W(L)  ((const void*)d_in[1 + ((L) - 1) * 4])
    #define B(L)  ((const void*)d_in[2 + ((L) - 1) * 4])
    #define G(L)  ((const void*)d_in[3 + ((L) - 1) * 4])
    #define BT(L) ((const void*)d_in[4 + ((L) - 1) * 4])

    float* stats = (float*)d_out;          // 384 floats; flag at [380]
    const float* flagp = stats + 380;
    float* wt1 = stats + 384;              // L1 fp32 [tap][co], 1936 floats
    bf16* wb2 = (bf16*)(wt1 + 1936);       // 50*256 bf16 (byte off 9280, 16-al)
    bf16* wb3 = wb2 + 50 * 256;            // 26*256
    bf16* wb4 = wb3 + 26 * 256;            // 10*256
    bf16* wb5 = wb4 + 10 * 256;            // 10*256
    const size_t need = 2 * (size_t)64 * HW * sizeof(bf16);   // exactly 256 MiB

    zeroStats<<<2, 256, 0, stream>>>(stats);
    probeKernel<<<1, 256, 0, stream>>>((const unsigned short*)x, stats);

    if (ws_size < need) {
        fillOut<<<2048, 256, 0, stream>>>(d_out, flagp, 3.0f);  // diagnostic
        return;
    }

    transposeW<<<8, 256, 0, stream>>>(W(1), wt1, 121, flagp);
    transposeWB<<<50, 256, 0, stream>>>(W(2), wb2, 49, 50, flagp);
    transposeWB<<<26, 256, 0, stream>>>(W(3), wb3, 25, 26, flagp);
    transposeWB<<<10, 256, 0, stream>>>(W(4), wb4, 9, 10, flagp);
    transposeWB<<<10, 256, 0, stream>>>(W(5), wb5, 9, 10, flagp);

    bf16* bufA = (bf16*)d_ws;              // 128 MiB
    bf16* bufB = bufA + 64 * HW;           // 128 MiB
    float* mirror = (float*)bufA;          // written only after bufA is dead

    dim3 grid(32, 32, 4), block(256);

    convFirst<<<grid, block, 0, stream>>>(x, wt1, B(1), bufA, stats + 0, flagp);
    finalizeStats<<<1, 64, 0, stream>>>(stats + 0, G(1), BT(1), 121.f, 16, nullptr, flagp);

    conv16m<7, 11><<<grid, block, 0, stream>>>(bufA, x, wb2, stats + 0, B(2), bufB, stats + 64, flagp);
    finalizeStats<<<1, 64, 0, stream>>>(stats + 64, G(2), BT(2), 49.f, 16, nullptr, flagp);

    conv16m<5, 17><<<grid, block, 0, stream>>>(bufB, x, wb3, stats + 64, B(3), bufA, stats + 128, flagp);
    finalizeStats<<<1, 64, 0, stream>>>(stats + 128, G(3), BT(3), 25.f, 16, nullptr, flagp);

    conv16m<3, 21><<<grid, block, 0, stream>>>(bufA, x, wb4, stats + 128, B(4), bufB, stats + 192, flagp);
    finalizeStats<<<1, 64, 0, stream>>>(stats + 192, G(4), BT(4), 9.f, 16, nullptr, flagp);

    conv16m<3, 23><<<grid, block, 0, stream>>>(bufB, x, wb5, stats + 192, B(5), bufA, stats + 256, flagp);
    finalizeStats<<<1, 64, 0, stream>>>(stats + 256, G(5), BT(5), 9.f, 16, nullptr, flagp);

    bf16* y6 = (bf16*)bufB;                // 8 MiB scratch in dead bufB
    layer6Kernel<<<grid, block, 0, stream>>>(bufA, x, stats + 256, W(6), B(6), y6, stats + 320, flagp);
    finalizeStats<<<1, 64, 0, stream>>>(stats + 320, G(6), BT(6), 1.f, 1, mirror, flagp);
    finalOut<<<2048, 256, 0, stream>>>(y6, mirror, d_out);

    #undef W
    #undef B
    #undef G
    #undef BT
}

// Round 10
// 1178.369 us; speedup vs baseline: 11.2725x; 1.1362x over previous
//
#include <hip/hip_runtime.h>
#include <hip/hip_bf16.h>

// SparseConvNet on MI355X — Round 10: convFirst occupancy fix.
// R9: conv16m MFMA rewrite -> total 1339us; top dispatch now convFirst
// (420us, VGPR=212 -> 2 waves/SIMD, VALUBusy 39%). Fix: unroll-1 tap loops
// (stop weight hoisting), __launch_bounds__(256,4) (target <=128 VGPR,
// 4 waves/SIMD), separable mask window-sum (484 -> ~60 adds/thread).
// VALU floor 103us; predict ~170us, total ~1080us. Everything else frozen.

#define HW (1024 * 1024)
typedef __hip_bfloat16 bf16;
typedef __attribute__((ext_vector_type(8))) short s8v;     // 8 bf16 = 4 VGPR
typedef __attribute__((ext_vector_type(4))) float f4v;     // MFMA acc

__device__ __forceinline__ float b2f(bf16 v) { return __bfloat162float(v); }
__device__ __forceinline__ bf16  f2b(float v) { return __float2bfloat16(v); }
__device__ __forceinline__ short fbits(float v) {
    bf16 t = f2b(v); short s; __builtin_memcpy(&s, &t, 2); return s;
}

__device__ __forceinline__ float ldv(const void* p, int i, bool isf) {
    return isf ? ((const float*)p)[i] : b2f(((const bf16*)p)[i]);
}

__device__ __forceinline__ float wave_reduce(float v) {
    #pragma unroll
    for (int off = 32; off > 0; off >>= 1)
        v += __shfl_down(v, off, 64);
    return v;
}

// ---------------- dtype probe: 1.0 = fp32 dataset, 0.0 = bf16 ----------------
__global__ void probeKernel(const unsigned short* __restrict__ xb,
                            float* __restrict__ stats)
{
    __shared__ int sbad;
    const int tid = threadIdx.x;
    if (tid == 0) sbad = 0;
    __syncthreads();
    int bad = 0;
    for (int i = tid; i < 4096; i += 256) {
        unsigned u = ((unsigned)xb[i]) << 16;
        float v = __uint_as_float(u);
        if (!(v >= 0.f && v < 1.f)) bad = 1;
    }
    if (bad) sbad = 1;
    __syncthreads();
    if (tid == 0) stats[380] = sbad ? 1.f : 0.f;
}

// ---- L1 weights: wt[(tap)*16+co] = w[co][tap], fp32 -------------------------
__global__ void transposeW(const void* __restrict__ w, float* __restrict__ wt,
                           int CINKK, const float* flagp)
{
    const bool isf = (*flagp > 0.5f);
    int j = blockIdx.x * 256 + threadIdx.x;
    if (j < 16 * CINKK) {
        int co = j / CINKK, r = j - co * CINKK;
        wt[r * 16 + co] = ldv(w, j, isf);
    }
}

// ---- L2-5 weights for MFMA B: wtB[((t*16+co)*16)+c] = w[co][c][t], bf16 -----
__global__ void transposeWB(const void* __restrict__ w, bf16* __restrict__ wtB,
                            int KK, int NT, const float* flagp)
{
    const bool isf = (*flagp > 0.5f);
    int j = blockIdx.x * 256 + threadIdx.x;
    if (j < NT * 256) {
        int t = j >> 8, co = (j >> 4) & 15, c = j & 15;
        float v = (t < KK) ? ldv(w, (co * 16 + c) * KK + t, isf) : 0.f;
        wtB[j] = f2b(v);
    }
}

// ---------------- composed mask tile (separable max over WP window) ----------
template <int TM, int TK, int WP>
__device__ __forceinline__ void buildMaskTile(
    const void* __restrict__ mask0, bool isf, float* sm0, float* vm,
    float* mprev, int bx, int by, int tid)
{
    constexpr int H1 = (TM - 32) / 2;
    constexpr int H2 = (TK - 32) / 2;
    for (int i = tid; i < TM * TM; i += 256) {
        int yy = by - H1 + i / TM, xx = bx - H1 + i % TM;
        float m = 0.f;
        if ((unsigned)yy < 1024u && (unsigned)xx < 1024u)
            m = ldv(mask0, (yy << 10) + xx, isf);
        sm0[i] = m;
    }
    __syncthreads();
    for (int i = tid; i < TK * TM; i += 256) {
        int y = i / TM, xc = i % TM;
        float mx = 0.f;
        for (int d = 0; d < WP; ++d) mx = fmaxf(mx, sm0[(y + d) * TM + xc]);
        vm[i] = mx;
    }
    __syncthreads();
    for (int i = tid; i < TK * TK; i += 256) {
        int y = i / TK, xc = i % TK;
        int gy = by - H2 + y, gx = bx - H2 + xc;
        float mx = 0.f;
        if ((unsigned)gy < 1024u && (unsigned)gx < 1024u)
            for (int d = 0; d < WP; ++d) mx = fmaxf(mx, vm[y * TM + xc + d]);
        mprev[i] = mx;
    }
    __syncthreads();
}

__device__ __forceinline__ const void* maskChanPtr(const void* x, int n, bool isf) {
    return isf ? (const void*)((const float*)x + n * 2 * HW + HW)
               : (const void*)((const bf16*)x + n * 2 * HW + HW);
}

// ---------------- layer 1: cin=1, K=11 (VALU, occupancy-tuned) ---------------
__global__ __launch_bounds__(256, 4) void convFirst(
    const void* __restrict__ x, const float* __restrict__ wt,
    const void* __restrict__ bias, bf16* __restrict__ out,
    float* statsCur, const float* flagp)
{
    constexpr int K = 11, P = 5, TK = 42, KK = 121;
    __shared__ float sdat[TK * TK];
    __shared__ float smask[TK * TK];
    __shared__ float scs[32 * TK];        // separable column sums
    __shared__ float swt[KK * 16];
    __shared__ float red[128];
    __shared__ float sbv[16];
    const bool isf = (*flagp > 0.5f);
    const int n = blockIdx.z;
    const int bx = blockIdx.x * 32, by = blockIdx.y * 32;
    const int tid = threadIdx.x;
    const int tx = tid & 31, ty0 = (tid >> 5) << 2;

    if (tid < 16) sbv[tid] = ldv(bias, tid, isf);
    {
        const float4* g4 = (const float4*)wt;
        float4* s4 = (float4*)swt;
        for (int i = tid; i < KK * 4; i += 256) s4[i] = g4[i];
    }

    const int xoff = n * 2 * HW;
    for (int i = tid; i < TK * TK; i += 256) {
        int yy = by - P + i / TK, xx = bx - P + i % TK;
        float d = 0.f, m = 0.f;
        if ((unsigned)yy < 1024u && (unsigned)xx < 1024u) {
            d = ldv(x, xoff + (yy << 10) + xx, isf);
            m = ldv(x, xoff + HW + (yy << 10) + xx, isf);
        }
        sdat[i] = d * m;
        smask[i] = m;
    }
    __syncthreads();

    // separable window sum: column pass then row pass
    for (int i = tid; i < 32 * TK; i += 256) {
        int r = i / TK, xc = i % TK;
        float s = 0.f;
        #pragma unroll
        for (int dy = 0; dy < K; ++dy) s += smask[(r + dy) * TK + xc];
        scs[i] = s;
    }
    __syncthreads();

    float inv[4];
    #pragma unroll
    for (int p = 0; p < 4; ++p) {
        float s = 0.f;
        #pragma unroll
        for (int dx = 0; dx < K; ++dx) s += scs[(ty0 + p) * TK + tx + dx];
        inv[p] = 121.f / (s + 1e-8f);
    }

    float acc[4][16];
    #pragma unroll
    for (int p = 0; p < 4; ++p)
        #pragma unroll
        for (int co = 0; co < 16; ++co) acc[p][co] = 0.f;

    #pragma unroll 1
    for (int dy = 0; dy < K; ++dy) {
        #pragma unroll 1
        for (int dx = 0; dx < K; ++dx) {
            const float* wr = swt + ((dy * K + dx) << 4);
            float4 wA = *(const float4*)(wr);
            float4 wB = *(const float4*)(wr + 4);
            float4 wC = *(const float4*)(wr + 8);
            float4 wD = *(const float4*)(wr + 12);
            const float* sp = sdat + (ty0 + dy) * TK + tx + dx;
            #pragma unroll
            for (int p = 0; p < 4; ++p) {
                float v = sp[p * TK];
                acc[p][0]  = fmaf(v, wA.x, acc[p][0]);
                acc[p][1]  = fmaf(v, wA.y, acc[p][1]);
                acc[p][2]  = fmaf(v, wA.z, acc[p][2]);
                acc[p][3]  = fmaf(v, wA.w, acc[p][3]);
                acc[p][4]  = fmaf(v, wB.x, acc[p][4]);
                acc[p][5]  = fmaf(v, wB.y, acc[p][5]);
                acc[p][6]  = fmaf(v, wB.z, acc[p][6]);
                acc[p][7]  = fmaf(v, wB.w, acc[p][7]);
                acc[p][8]  = fmaf(v, wC.x, acc[p][8]);
                acc[p][9]  = fmaf(v, wC.y, acc[p][9]);
                acc[p][10] = fmaf(v, wC.z, acc[p][10]);
                acc[p][11] = fmaf(v, wC.w, acc[p][11]);
                acc[p][12] = fmaf(v, wD.x, acc[p][12]);
                acc[p][13] = fmaf(v, wD.y, acc[p][13]);
                acc[p][14] = fmaf(v, wD.z, acc[p][14]);
                acc[p][15] = fmaf(v, wD.w, acc[p][15]);
            }
        }
    }

    float csum[16], csq[16];
    #pragma unroll
    for (int co = 0; co < 16; ++co) { csum[co] = 0.f; csq[co] = 0.f; }
    #pragma unroll
    for (int p = 0; p < 4; ++p) {
        int yy = by + ty0 + p, xx = bx + tx;
        #pragma unroll
        for (int co = 0; co < 16; ++co) {
            float y = fmaf(acc[p][co], inv[p], sbv[co]);
            out[(n * 16 + co) * HW + (yy << 10) + xx] = f2b(y);
            csum[co] += y;
            csq[co] = fmaf(y, y, csq[co]);
        }
    }
    const int wid = tid >> 6, lane = tid & 63;
    #pragma unroll
    for (int co = 0; co < 16; ++co) {
        csum[co] = wave_reduce(csum[co]);
        csq[co]  = wave_reduce(csq[co]);
    }
    if (lane == 0) {
        #pragma unroll
        for (int co = 0; co < 16; ++co) {
            red[wid * 32 + co]      = csum[co];
            red[wid * 32 + 16 + co] = csq[co];
        }
    }
    __syncthreads();
    if (tid < 32) {
        float t = red[tid] + red[32 + tid] + red[64 + tid] + red[96 + tid];
        atomicAdd(&statsCur[tid], t);
    }
}

// ---------------- layers 2..5: MFMA implicit-GEMM (unchanged from R9) --------
template <int K, int WP>
__global__ __launch_bounds__(256) void conv16m(
    const bf16* __restrict__ in, const void* __restrict__ x,
    const bf16* __restrict__ wtB, const float* statsPrev,
    const void* __restrict__ bias, bf16* __restrict__ out,
    float* statsCur, const float* flagp)
{
    constexpr int TK = 32 + K - 1;
    constexpr int TM = TK + WP - 1;
    constexpr int KK = K * K, NT = KK + 1, NK = NT / 2;
    constexpr int H2 = K / 2;
    __shared__ short sdatL[TK * TK * 8];
    __shared__ short sdatH[TK * TK * 8];
    __shared__ float mprev[TK * TK];
    __shared__ float sinv[1024];
    __shared__ float red[128];
    __shared__ float sss[32];
    const bool isf = (*flagp > 0.5f);
    const int n = blockIdx.z;
    const int bx = blockIdx.x * 32, by = blockIdx.y * 32;
    const int tid = threadIdx.x, lane = tid & 63, wid = tid >> 6;

    if (tid < 16) { sss[tid] = statsPrev[32 + tid]; sss[16 + tid] = statsPrev[48 + tid]; }

    buildMaskTile<TM, TK, WP>(maskChanPtr(x, n, isf), isf,
                              (float*)sdatL, (float*)sdatH, mprev, bx, by, tid);

    {
        const int tx = tid & 31, ty0 = (tid >> 5) << 2;
        #pragma unroll
        for (int p = 0; p < 4; ++p) {
            float s = 0.f;
            for (int dy = 0; dy < K; ++dy)
                #pragma unroll
                for (int dx = 0; dx < K; ++dx)
                    s += mprev[(ty0 + p + dy) * TK + tx + dx];
            sinv[(ty0 + p) * 32 + tx] = (float)KK / (s + 1e-8f);
        }
    }

    const int nn = lane & 15, quad = lane >> 4, c0 = (quad & 1) * 8, tl = quad >> 1;
    s8v Bf[NK];
    #pragma unroll
    for (int kk = 0; kk < NK; ++kk) {
        int t = 2 * kk + tl;
        Bf[kk] = *(const s8v*)(wtB + ((t * 16 + nn) * 16 + c0));
    }

    {
        const bf16* inb = in + (size_t)n * 16 * HW;
        for (int p = tid; p < TK * TK; p += 256) {
            int yy = by - H2 + p / TK, xx = bx - H2 + p % TK;
            s8v lo = {0,0,0,0,0,0,0,0}, hi = {0,0,0,0,0,0,0,0};
            if ((unsigned)yy < 1024u && (unsigned)xx < 1024u) {
                float mv = mprev[p];
                const bf16* q = inb + (yy << 10) + xx;
                #pragma unroll
                for (int c = 0; c < 8; ++c) {
                    float yv = b2f(q[c * HW]);
                    lo[c] = fbits(fmaxf(fmaf(sss[c], yv, sss[16 + c]), 0.f) * mv);
                }
                #pragma unroll
                for (int c = 0; c < 8; ++c) {
                    float yv = b2f(q[(c + 8) * HW]);
                    hi[c] = fbits(fmaxf(fmaf(sss[c + 8], yv, sss[24 + c]), 0.f) * mv);
                }
            }
            ((s8v*)sdatL)[p] = lo;
            ((s8v*)sdatH)[p] = hi;
        }
    }
    __syncthreads();

    const float bv = ldv(bias, nn, isf);
    const s8v* Abase = (const s8v*)((quad & 1) ? sdatH : sdatL);
    const size_t obase = ((size_t)n * 16 + nn) * HW;
    float lsum = 0.f, lsq = 0.f;

    for (int mt = 0; mt < 16; ++mt) {
        int idx = wid * 16 + mt;
        int r = idx >> 1, xh = (idx & 1) << 4;
        int acol = xh + nn;
        f4v acc0 = {0.f, 0.f, 0.f, 0.f}, acc1 = {0.f, 0.f, 0.f, 0.f};
        #pragma unroll
        for (int kk = 0; kk < NK; ++kk) {
            const int ta = (2 * kk < KK) ? 2 * kk : 0;
            const int tb = (2 * kk + 1 < KK) ? 2 * kk + 1 : 0;
            const int dya = ta / K, dxa = ta % K;
            const int dyb = tb / K, dxb = tb % K;
            int dy = tl ? dyb : dya;
            int dx = tl ? dxb : dxa;
            s8v a = Abase[(r + dy) * TK + acol + dx];
            if (kk & 1)
                acc1 = __builtin_amdgcn_mfma_f32_16x16x32_bf16(a, Bf[kk], acc1, 0, 0, 0);
            else
                acc0 = __builtin_amdgcn_mfma_f32_16x16x32_bf16(a, Bf[kk], acc0, 0, 0, 0);
        }
        #pragma unroll
        for (int i = 0; i < 4; ++i) {
            float av = acc0[i] + acc1[i];
            int m = quad * 4 + i;
            float y = fmaf(av, sinv[r * 32 + xh + m], bv);
            out[obase + ((by + r) << 10) + bx + xh + m] = f2b(y);
            lsum += y;
            lsq = fmaf(y, y, lsq);
        }
    }

    lsum += __shfl_xor(lsum, 16, 64);
    lsum += __shfl_xor(lsum, 32, 64);
    lsq  += __shfl_xor(lsq, 16, 64);
    lsq  += __shfl_xor(lsq, 32, 64);
    if (lane < 16) {
        red[wid * 32 + lane]      = lsum;
        red[wid * 32 + 16 + lane] = lsq;
    }
    __syncthreads();
    if (tid < 32) {
        float t = red[tid] + red[32 + tid] + red[64 + tid] + red[96 + tid];
        atomicAdd(&statsCur[tid], t);
    }
}

// ---------------- layer 6: 1x1 conv to 1 channel -----------------------------
__global__ __launch_bounds__(256) void layer6Kernel(
    const bf16* __restrict__ in, const void* __restrict__ x,
    const float* statsPrev, const void* __restrict__ w6,
    const void* __restrict__ b6, bf16* __restrict__ y6,
    float* statsCur, const float* flagp)
{
    constexpr int WP = 25, TM = 56, TK = 32;
    __shared__ float sm0[TM * TM];
    __shared__ float vm[TK * TM];
    __shared__ float m5[TK * TK];
    __shared__ float red[8];
    __shared__ float ssc[16], ssh[16];
    const bool isf = (*flagp > 0.5f);
    const int n = blockIdx.z;
    const int bx = blockIdx.x * 32, by = blockIdx.y * 32;
    const int tid = threadIdx.x;
    const int tx = tid & 31, ty0 = (tid >> 5) << 2;

    if (tid < 16) {
        ssc[tid] = statsPrev[32 + tid];
        ssh[tid] = statsPrev[48 + tid];
    }

    buildMaskTile<TM, TK, WP>(maskChanPtr(x, n, isf), isf, sm0, vm, m5, bx, by, tid);

    float wv[16];
    #pragma unroll
    for (int c = 0; c < 16; ++c) wv[c] = ldv(w6, c, isf);
    const float bias = ldv(b6, 0, isf);

    float lsum = 0.f, lsq = 0.f;
    #pragma unroll
    for (int p = 0; p < 4; ++p) {
        int yy = by + ty0 + p, xx = bx + tx;
        float m = m5[(ty0 + p) * TK + tx];
        float a = 0.f;
        #pragma unroll
        for (int c = 0; c < 16; ++c) {
            float y = b2f(in[(n * 16 + c) * HW + (yy << 10) + xx]);
            float h = fmaxf(fmaf(ssc[c], y, ssh[c]), 0.f);
            a = fmaf(h, wv[c], a);
        }
        float yv = a * m / (m + 1e-8f) + bias;
        y6[n * HW + (yy << 10) + xx] = f2b(yv);
        lsum += yv;
        lsq = fmaf(yv, yv, lsq);
    }
    lsum = wave_reduce(lsum);
    lsq = wave_reduce(lsq);
    const int wid = tid >> 6, lane = tid & 63;
    if (lane == 0) { red[wid] = lsum; red[4 + wid] = lsq; }
    __syncthreads();
    if (tid == 0) atomicAdd(&statsCur[0],  red[0] + red[1] + red[2] + red[3]);
    if (tid == 1) atomicAdd(&statsCur[16], red[4] + red[5] + red[6] + red[7]);
}

// ---------------- helpers ----------------------------------------------------
__global__ void finalizeStats(float* stats, const void* __restrict__ g,
                              const void* __restrict__ bt, float alpha, int cout,
                              float* mirror, const float* flagp)
{
    const bool isf = (*flagp > 0.5f);
    int c = threadIdx.x;
    if (c < cout) {
        const float invN = 1.f / (4.f * HW);
        float meanp = stats[c] * invN;
        float varp  = fmaxf(stats[16 + c] * invN - meanp * meanp, 0.f);
        float var_t = varp / (alpha * alpha);
        float sct = ldv(g, c, isf) * rsqrtf(var_t + 1e-5f);
        float scp = sct / alpha;
        float shp = ldv(bt, c, isf) - scp * meanp;
        stats[32 + c] = scp;
        stats[48 + c] = shp;
        if (mirror) { mirror[2 * c] = scp; mirror[2 * c + 1] = shp; mirror[32] = isf ? 1.f : 0.f; }
    }
}

__global__ void finalOut(const bf16* __restrict__ y6, const float* mirror,
                         void* __restrict__ out)
{
    float sc = mirror[0], sh = mirror[1];
    const bool isf = (mirror[32] > 0.5f);
    for (int idx = blockIdx.x * 256 + threadIdx.x; idx < 4 * HW; idx += gridDim.x * 256) {
        float v = fmaf(b2f(y6[idx]), sc, sh);
        if (isf) ((float*)out)[idx] = v;
        else     ((bf16*)out)[idx] = f2b(v);
    }
}

__global__ void zeroStats(float* stats)
{
    int i = blockIdx.x * 256 + threadIdx.x;
    if (i < 384) stats[i] = 0.f;
}

__global__ void fillOut(void* out, const float* flagp, float v)
{
    const bool isf = (*flagp > 0.5f);
    for (int idx = blockIdx.x * 256 + threadIdx.x; idx < 4 * HW; idx += gridDim.x * 256) {
        if (isf) ((float*)out)[idx] = v;
        else     ((bf16*)out)[idx] = f2b(v);
    }
}

// ---------------- launch ------------------------------------------------------
extern "C" void kernel_launch(void* const* d_in, const int* in_sizes, int n_in,
                              void* d_out, int out_size, void* d_ws, size_t ws_size,
                              hipStream_t stream)
{
    const void* x = d_in[0];
    #define W(L)  ((const void*)d_in[1 + ((L) - 1) * 4])
    #define B(L)  ((const void*)d_in[2 + ((L) - 1) * 4])
    #define G(L)  ((const void*)d_in[3 + ((L) - 1) * 4])
    #define BT(L) ((const void*)d_in[4 + ((L) - 1) * 4])

    float* stats = (float*)d_out;
    const float* flagp = stats + 380;
    float* wt1 = stats + 384;
    bf16* wb2 = (bf16*)(wt1 + 1936);
    bf16* wb3 = wb2 + 50 * 256;
    bf16* wb4 = wb3 + 26 * 256;
    bf16* wb5 = wb4 + 10 * 256;
    const size_t need = 2 * (size_t)64 * HW * sizeof(bf16);

    zeroStats<<<2, 256, 0, stream>>>(stats);
    probeKernel<<<1, 256, 0, stream>>>((const unsigned short*)x, stats);

    if (ws_size < need) {
        fillOut<<<2048, 256, 0, stream>>>(d_out, flagp, 3.0f);
        return;
    }

    transposeW<<<8, 256, 0, stream>>>(W(1), wt1, 121, flagp);
    transposeWB<<<50, 256, 0, stream>>>(W(2), wb2, 49, 50, flagp);
    transposeWB<<<26, 256, 0, stream>>>(W(3), wb3, 25, 26, flagp);
    transposeWB<<<10, 256, 0, stream>>>(W(4), wb4, 9, 10, flagp);
    transposeWB<<<10, 256, 0, stream>>>(W(5), wb5, 9, 10, flagp);

    bf16* bufA = (bf16*)d_ws;
    bf16* bufB = bufA + 64 * HW;
    float* mirror = (float*)bufA;

    dim3 grid(32, 32, 4), block(256);

    convFirst<<<grid, block, 0, stream>>>(x, wt1, B(1), bufA, stats + 0, flagp);
    finalizeStats<<<1, 64, 0, stream>>>(stats + 0, G(1), BT(1), 121.f, 16, nullptr, flagp);

    conv16m<7, 11><<<grid, block, 0, stream>>>(bufA, x, wb2, stats + 0, B(2), bufB, stats + 64, flagp);
    finalizeStats<<<1, 64, 0, stream>>>(stats + 64, G(2), BT(2), 49.f, 16, nullptr, flagp);

    conv16m<5, 17><<<grid, block, 0, stream>>>(bufB, x, wb3, stats + 64, B(3), bufA, stats + 128, flagp);
    finalizeStats<<<1, 64, 0, stream>>>(stats + 128, G(3), BT(3), 25.f, 16, nullptr, flagp);

    conv16m<3, 21><<<grid, block, 0, stream>>>(bufA, x, wb4, stats + 128, B(4), bufB, stats + 192, flagp);
    finalizeStats<<<1, 64, 0, stream>>>(stats + 192, G(4), BT(4), 9.f, 16, nullptr, flagp);

    conv16m<3, 23><<<grid, block, 0, stream>>>(bufB, x, wb5, stats + 192, B(5), bufA, stats + 256, flagp);
    finalizeStats<<<1, 64, 0, stream>>>(stats + 256, G(5), BT(5), 9.f, 16, nullptr, flagp);

    bf16* y6 = (bf16*)bufB;
    layer6Kernel<<<grid, block, 0, stream>>>(bufA, x, stats + 256, W(6), B(6), y6, stats + 320, flagp);
    finalizeStats<<<1, 64, 0, stream>>>(stats + 320, G(6), BT(6), 1.f, 1, mirror, flagp);
    finalOut<<<2048, 256, 0, stream>>>(y6, mirror, d_out);

    #undef W
    #undef B
    #undef G
    #undef BT
}